// Round 17
// baseline (2719.821 us; speedup 1.0000x reference)
//
#include <hip/hip_runtime.h>
#include <math.h>

// TD3ActorDSNN — f32 class-faithful, fused, round 17.
// Exactness invariants (validated r4-r6, r9, r11-r16):
//  - per-element k-ascending single-accumulator f32 chains for h0 and h1;
//    skipping k with mask==0 is bit-identical; per-chain k-order fixed.
//  - b in {0,1}: fma(b,w,acc) EXACT; v_pk_fma_f32 = two independent IEEE
//    fmas on the two column sub-chains -> same chains, bit-identical.
//  - masks periodic (mem0 resets to exact 0): n = ctz+1; bit t = ((t+1)%n==0).
//  - recurrences: __fadd_rn(__fmul_rn(beta,state),h) (np mul-then-add).
//  - layer2/mem2: order-free (tanh input, tol 2e-2 >> 1e-6 noise).
// Codegen ledger:
//  SPILL: any branch/asm on the 60 live accs (r7/r8/r13/r15); VGPR cap from
//    launch_bounds(,8) (r10). SAFE: single-BB portable body at (256,4).
//  r14: dense per-entry SALU selects saturate the CU-shared scalar pipe.
//  r16: b from 1KB LUT (s_loaded) -> 83 VALU/entry, 2.65ms, 83% busy.
//  r9/r12: f32x2 scalarized when b was splat-BUILT per lane.
// Round-17: b splat PRECOMPUTED in memory — dup-LUT rows [b0,b0,b1,b1,...]
// (16 x 32 f32). All efma operands are load-fed <2 x float> -> the LLVM
// pattern for v_pk_fma_f32. 30 pk/entry instead of 60 scalar fma.
// 1 entry/iter keeps worst-case VGPR ~105 < 128.

typedef unsigned int u32;
typedef unsigned short u16;
typedef unsigned long long u64;
typedef __attribute__((ext_vector_type(2))) float f32x2;

// ---- K1: h0 = inputs @ W0 (f32 fma chain) + fused mem0 recurrence -> s0bR ----
__global__ __launch_bounds__(256) void h0_kernel(
    const float* __restrict__ in, const float* __restrict__ W0,
    u16* __restrict__ s0bR) {
    __shared__ float Ls[32 * 512];
    int tid = threadIdx.x;
    int j = blockIdx.x * 256 + tid;
    int r0 = blockIdx.y * 32;
#pragma unroll
    for (int i = 0; i < 64; ++i) {
        int e = i * 256 + tid;
        Ls[e] = in[(size_t)(r0 + (e >> 9)) * 512 + (e & 511)];
    }
    __syncthreads();
    float acc[32];
#pragma unroll
    for (int r = 0; r < 32; ++r) acc[r] = 0.f;
    for (int k = 0; k < 512; ++k) {
        float w = W0[(size_t)k * 2048 + j];
#pragma unroll
        for (int r = 0; r < 32; ++r)
            acc[r] = __fmaf_rn(Ls[r * 512 + k], w, acc[r]);
    }
#pragma unroll
    for (int r = 0; r < 32; ++r) {
        float h = acc[r], mem = 0.f;
        u32 bits = 0;
#pragma unroll
        for (int t = 0; t < 15; ++t) {
            float nm = __fadd_rn(__fmul_rn(0.85f, mem), h);  // np: mul, then add
            bool sp = nm > 1.0f;
            bits |= (sp ? 1u : 0u) << t;
            mem = sp ? 0.f : nm;
        }
        s0bR[(size_t)(r0 + r) * 2048 + j] = (u16)bits;
    }
}

// ---- K1b: active-k compaction (k-ascending) + dup b-LUT init ----
// entry = k<<16 | n, n = ctz(mask)+1. lutd[n][2t] = lutd[n][2t+1] = bit t.
__global__ __launch_bounds__(256) void compact_kernel(
    const u16* __restrict__ s0bR, u32* __restrict__ list,
    int* __restrict__ ccnt, float* __restrict__ lutd) {
    int wv = threadIdx.x >> 6, lane = threadIdx.x & 63;
    if (blockIdx.x == 0) {    // fill 16x32 dup LUT
        int n = threadIdx.x >> 4, t = threadIdx.x & 15;
        float v = (n >= 1 && t < 15 && ((t + 1) % n == 0)) ? 1.0f : 0.0f;
        lutd[n * 32 + 2 * t] = v;
        lutd[n * 32 + 2 * t + 1] = v;
    }
    int row = blockIdx.x * 4 + wv;
    const u16* mrow = s0bR + (size_t)row * 2048;
    u32* lrow = list + (size_t)row * 2048;
    int base = 0;
    for (int c = 0; c < 32; ++c) {
        int k = c * 64 + lane;
        u32 m = mrow[k];
        bool act = m != 0u;
        u64 b = __ballot(act ? 1 : 0);
        int pre = __popcll(b & ((1ull << lane) - 1ull));
        if (act) lrow[base + pre] = ((u32)k << 16) | (u32)(__builtin_ctz(m | 0x10000u) + 1);
        base += __popcll(b);
    }
    // no padding needed (1 entry per iter), but keep count exact
    if (lane == 0) ccnt[row] = base;
}

// ---- K2: FUSED h1 (15 steps) over ACTIVE k only + recurrence -> s1b ----
// Wave: 1 row x 256 cols (lane: 4 cols = 2 col-pairs). Block: 4 rows.
// grid 8192: jb = id&7 (XCD-affine W1 slice), rblk = id>>3.
// Single-BB body: per entry 8 b-float4 loads (uniform -> SGPR) + 1 w float4
// + 30 pk_fma. All efma operands load-fed <2 x float>.
__global__ __launch_bounds__(256, 4) void h1_fused13(
    const float* __restrict__ W1, const u32* __restrict__ list,
    const int* __restrict__ ccnt, const float* __restrict__ lutd,
    u16* __restrict__ s1b) {
    int id = blockIdx.x;
    int jb = id & 7, rblk = id >> 3;
    int lane = threadIdx.x & 63, wv = threadIdx.x >> 6;
    int row = rblk * 4 + wv;
    int j0 = jb * 256 + lane * 4;
    const float* wp = W1 + j0;
    const u32* lp = list + (size_t)row * 2048;
    int cnt = ccnt[row];

    f32x2 acc[15][2];
#pragma unroll
    for (int t = 0; t < 15; ++t) {
        acc[t][0] = (f32x2){0.f, 0.f};
        acc[t][1] = (f32x2){0.f, 0.f};
    }

    for (int i = 0; i < cnt; ++i) {
        u32 s = __builtin_amdgcn_readfirstlane(lp[i]);   // k<<16 | n
        float4 w = *(const float4*)(wp + ((size_t)(s >> 16) << 11));
        const float4* bq = (const float4*)(lutd + ((s & 15u) << 5));
        float4 c0 = bq[0], c1 = bq[1], c2 = bq[2], c3 = bq[3];
        float4 c4 = bq[4], c5 = bq[5], c6 = bq[6], c7 = bq[7];
        f32x2 W01 = {w.x, w.y}, W23 = {w.z, w.w};
#define STEP2(T, BB)                                                   \
        acc[T][0] = __builtin_elementwise_fma(BB, W01, acc[T][0]);     \
        acc[T][1] = __builtin_elementwise_fma(BB, W23, acc[T][1]);
        { f32x2 B; B = (f32x2){c0.x, c0.y}; STEP2(0, B)
                   B = (f32x2){c0.z, c0.w}; STEP2(1, B)
                   B = (f32x2){c1.x, c1.y}; STEP2(2, B)
                   B = (f32x2){c1.z, c1.w}; STEP2(3, B)
                   B = (f32x2){c2.x, c2.y}; STEP2(4, B)
                   B = (f32x2){c2.z, c2.w}; STEP2(5, B)
                   B = (f32x2){c3.x, c3.y}; STEP2(6, B)
                   B = (f32x2){c3.z, c3.w}; STEP2(7, B)
                   B = (f32x2){c4.x, c4.y}; STEP2(8, B)
                   B = (f32x2){c4.z, c4.w}; STEP2(9, B)
                   B = (f32x2){c5.x, c5.y}; STEP2(10, B)
                   B = (f32x2){c5.z, c5.w}; STEP2(11, B)
                   B = (f32x2){c6.x, c6.y}; STEP2(12, B)
                   B = (f32x2){c6.z, c6.w}; STEP2(13, B)
                   B = (f32x2){c7.x, c7.y}; STEP2(14, B) }
#undef STEP2
    }

    // layer-1 recurrence per element (np rounding order) -> s1 bitmasks
    auto rec = [](float h1_0, float h1_1, float h1_2, float h1_3,
                  const f32x2 (*a)[2], int q) -> u16 {
        (void)h1_0; (void)h1_1; (void)h1_2; (void)h1_3;
        float syn = 0.f, mem = 0.f;
        u32 obits = 0;
#pragma unroll
        for (int t = 0; t < 15; ++t) {
            float h1 = a[t][q >> 1][q & 1];
            float ns = __fadd_rn(__fmul_rn(0.9f, syn), h1);
            float nm = __fadd_rn(__fmul_rn(0.85f, mem), ns);
            bool sp = nm > 1.0f;
            obits |= (sp ? 1u : 0u) << t;
            syn = ns;
            mem = sp ? 0.f : nm;
        }
        return (u16)obits;
    };
    u16 ob0 = rec(0, 0, 0, 0, acc, 0);
    u16 ob1 = rec(0, 0, 0, 0, acc, 1);
    u16 ob2 = rec(0, 0, 0, 0, acc, 2);
    u16 ob3 = rec(0, 0, 0, 0, acc, 3);
    uint2 pk;
    pk.x = (u32)ob0 | ((u32)ob1 << 16);
    pk.y = (u32)ob2 | ((u32)ob3 << 16);
    *(uint2*)(s1b + (size_t)row * 2048 + j0) = pk;
}

// ---- K3: out = tanh(sum_t s1_t @ W2) (order-free reduction) ----
__global__ __launch_bounds__(256) void out_kernel(
    const u16* __restrict__ s1b, const float* __restrict__ W2,
    float* __restrict__ out) {
    __shared__ float P[4][15][8];
    int row = blockIdx.x;
    int tid = threadIdx.x, lane = tid & 63, wv = tid >> 6;
    const u16* srow = s1b + (size_t)row * 2048;
    union { uint4 v; u16 m[8]; } u;
    u.v = *(const uint4*)(srow + tid * 8);
#pragma unroll
    for (int t = 0; t < 15; ++t) {
        float a[8];
#pragma unroll
        for (int jj = 0; jj < 8; ++jj) a[jj] = 0.f;
#pragma unroll
        for (int kk = 0; kk < 8; ++kk) {
            const float* wr = W2 + (size_t)(tid * 8 + kk) * 8;
            if ((u.m[kk] >> t) & 1u) {
#pragma unroll
                for (int jj = 0; jj < 8; ++jj)
                    a[jj] = __fadd_rn(a[jj], wr[jj]);
            }
        }
#pragma unroll
        for (int jj = 0; jj < 8; ++jj) {
            float v = a[jj];
#pragma unroll
            for (int m = 1; m < 64; m <<= 1) v += __shfl_xor(v, m, 64);
            a[jj] = v;
        }
        if (lane == 0) {
#pragma unroll
            for (int jj = 0; jj < 8; ++jj) P[wv][t][jj] = a[jj];
        }
    }
    __syncthreads();
    if (tid < 8) {
        float m2 = 0.f;
#pragma unroll
        for (int t = 0; t < 15; ++t) {
            float s = __fadd_rn(__fadd_rn(P[0][t][tid], P[1][t][tid]),
                                __fadd_rn(P[2][t][tid], P[3][t][tid]));
            m2 = __fadd_rn(m2, s);
        }
        out[(size_t)row * 8 + tid] = tanhf(m2);
    }
}

extern "C" void kernel_launch(void* const* d_in, const int* in_sizes, int n_in,
                              void* d_out, int out_size, void* d_ws, size_t ws_size,
                              hipStream_t stream) {
    const float* inp = (const float*)d_in[0];
    const float* W0  = (const float*)d_in[1];
    const float* W1  = (const float*)d_in[2];
    const float* W2  = (const float*)d_in[3];
    float* out = (float*)d_out;
    char* ws = (char*)d_ws;

    u16*   s0bR = (u16*)(ws + 0);          // 16,777,216  [row][k] 15-bit masks
    u16*   s1b  = (u16*)(ws + 16777216);   // 16,777,216  [row][j] 15-bit masks
    u32*   list = (u32*)(ws + 33554432);   // 33,554,432  [row][2048] (k<<16|n)
    int*   ccnt = (int*)(ws + 67108864);   //     16,384  counts
    float* lutd = (float*)(ws + 67125248); //      2,048  16x32 dup b-LUT
    if (ws_size < 67127296) return;        // ~64 MB scratch

    h0_kernel<<<dim3(8, 128), 256, 0, stream>>>(inp, W0, s0bR);
    compact_kernel<<<1024, 256, 0, stream>>>(s0bR, list, ccnt, lutd);
    h1_fused13<<<8192, 256, 0, stream>>>(W1, list, ccnt, lutd, s1b);
    out_kernel<<<4096, 256, 0, stream>>>(s1b, W2, out);
}